// Round 17
// baseline (462.747 us; speedup 1.0000x reference)
//
#include <hip/hip_runtime.h>

typedef __attribute__((ext_vector_type(8))) short bf16x8;
typedef __attribute__((ext_vector_type(4))) float f32x4;

__device__ __forceinline__ unsigned short f2bf(float f){
  unsigned u = __builtin_bit_cast(unsigned, f);
  u += 0x7fffu + ((u >> 16) & 1u);
  return (unsigned short)(u >> 16);
}

__device__ __forceinline__ unsigned cvt_pk_bf16(float lo, float hi){
  unsigned r;
  asm("v_cvt_pk_bf16_f32 %0, %1, %2" : "=v"(r) : "v"(lo), "v"(hi));
  return r;
}

#define ASYNC16(ldsp, gp) __builtin_amdgcn_global_load_lds( \
    (const __attribute__((address_space(1))) unsigned int*)(gp), \
    (__attribute__((address_space(3))) unsigned int*)(ldsp), 16, 0, 0)

// ---- fused prep (R15-proven) ----
// [0,37632): x fp32 -> bf16 window-ordered [win*49+n][384]
// [37632,37992): Wqkv -> bf16 FRAGMENT-MAJOR (fqa layout); Wout -> bf16 row-major
// [37992,38040): btab fragment-major, log2e-scaled, -inf mask k>=49.
__global__ __launch_bounds__(256) void prep_kernel(const float* __restrict__ x,
                                                   const float* __restrict__ wq,
                                                   const float* __restrict__ wo,
                                                   const float* __restrict__ rel_pos,
                                                   unsigned short* __restrict__ xb,
                                                   unsigned short* __restrict__ wqb,
                                                   unsigned short* __restrict__ wob,
                                                   float* __restrict__ btab){
  const int bid = blockIdx.x;
  if (bid < 37632){
    int idx = bid*256 + threadIdx.x;               // 100352*96 threads, 4 ch each
    int token = idx / 96, j = idx - token*96;
    int b = token / 3136, rem = token - b*3136;
    int rr = rem / 56, cp = rem - rr*56;
    int p = rr >> 3, h = rr & 7, q = cp >> 3, w = cp & 7;
    int orow = ((b*8 + h)*8 + w)*49 + p*7 + q;
    float4 v = *(const float4*)(x + (size_t)idx*4);
    ushort4 o;
    o.x = f2bf(v.x); o.y = f2bf(v.y); o.z = f2bf(v.z); o.w = f2bf(v.w);
    *(ushort4*)(xb + (size_t)orow*384 + j*4) = o;
  } else if (bid < 37992){
    int idx = (bid - 37632)*256 + threadIdx.x;     // 92160 threads
    if (idx < 55296){                              // Wqkv frag-major, 8 elems
      int lane = idx & 63;
      int r = idx >> 6;                            // 0..863
      int wt = r & 7; int r2 = r >> 3;             // 0..107
      int t = r2 % 12, gi = r2 / 12;               // gi 0..8
      int hgp = gi / 3, m = gi - hgp*3;
      int row = m*384 + hgp*128 + (wt>>1)*32 + (wt&1)*16 + (lane & 15);
      int col = t*32 + (lane >> 4)*8;
      const float* s = wq + (size_t)row*384 + col;
      float4 v1 = *(const float4*)(s);
      float4 v2 = *(const float4*)(s + 4);
      ushort4 o1, o2;
      o1.x=f2bf(v1.x); o1.y=f2bf(v1.y); o1.z=f2bf(v1.z); o1.w=f2bf(v1.w);
      o2.x=f2bf(v2.x); o2.y=f2bf(v2.y); o2.z=f2bf(v2.z); o2.w=f2bf(v2.w);
      unsigned short* dst = wqb + (size_t)idx*8;
      *(ushort4*)(dst)     = o1;
      *(ushort4*)(dst + 4) = o2;
    } else {                                       // Wout row-major, 4 elems
      int k = idx - 55296;                         // 36864 threads
      float4 v = *(const float4*)(wo + (size_t)k*4);
      ushort4 o; o.x=f2bf(v.x); o.y=f2bf(v.y); o.z=f2bf(v.z); o.w=f2bf(v.w);
      *(ushort4*)(wob + (size_t)k*4) = o;
    }
  } else {
    int idx = (bid - 37992)*256 + threadIdx.x;     // 12288 threads
    int head = idx >> 10, rem = idx & 1023;
    int fi = rem >> 6, lane = rem & 63;
    int ti = fi >> 2, tj = fi & 3;
    int qq = tj*16 + (lane & 15);
    int kb = ti*16 + (lane >> 4)*4;
    float4 v; float* vp = (float*)&v;
#pragma unroll
    for (int r=0; r<4; ++r){
      int kk = kb + r;
      float val;
      if (kk >= 49) val = -__builtin_inff();
      else if (qq >= 49) val = 0.f;
      else {
        int ip = qq/7, iq = qq - ip*7, jp = kk/7, jq = kk - jp*7;
        val = rel_pos[head*169 + (ip-jp+6)*13 + (iq-jq+6)] * 1.4426950408889634f;
      }
      vp[r] = val;
    }
    *(float4*)(btab + (size_t)idx*4) = v;
  }
}

// ---- FUSED qkv-projection + windowed attention, v3 ----
// v2 (R16) + LDS shrink 60->48KB: Al (dead after phase 1) and VT (written in
// phase 2) share one 16KB union, with a single __syncthreads() between the
// last Al read and the first VT write.  48KB -> 3 blocks/CU (was 2), pinned
// via __launch_bounds__(256,3).  Everything else identical to R16-verified.
__global__ __launch_bounds__(256, 3) void fqa_kernel(const unsigned short* __restrict__ xb,
                                                     const unsigned short* __restrict__ Wf,
                                                     const float* __restrict__ bqkv,
                                                     const float* __restrict__ btab,
                                                     unsigned short* __restrict__ ao)
{
  __shared__ unsigned short AV[8192];      // 16KB: Al[3][2048] (ph1) ∪ VT[4][2048] (ph2/3)
  __shared__ unsigned short QK[4][4096];   // 32KB [tok64][q32|k32] swizzled; reused as P
  const int tid = threadIdx.x, lane = tid & 63, wid = tid >> 6;
  const int l15 = lane & 15, kg = lane >> 4;
  const int win = blockIdx.x & 2047;
  const int hg  = blockIdx.x >> 11;              // 0..2
  const int head = hg*4 + wid;

  // ---- phase 1: qkv GEMM (M=64 window rows, per-wave N=32 dd-cols, K=384) ----
  int srowg = win*49 + (tid >> 2);
  if (srowg > 100351) srowg = 100351;            // finite clamp (last window)
  const int cswz = (tid & 3) ^ ((tid >> 3) & 3);
  const unsigned short* AgS = xb + (size_t)srowg*384 + cswz*8;
  const int rswz = (l15 >> 1) & 3;               // read-side chunk XOR

  const unsigned short* bp[3][2];
#pragma unroll
  for (int m=0; m<3; ++m)
#pragma unroll
    for (int tjj=0; tjj<2; ++tjj)
      bp[m][tjj] = Wf + ((size_t)((hg*3 + m)*12)*8 + wid*2 + tjj)*512 + lane*8;

  f32x4 aq[4][2] = {}, ak[4][2] = {}, av[4][2] = {};
  bf16x8 bq[2][2], bk[2][2], bv[2][2];

#define STAGE_A(buf, t) ASYNC16(&AV[(buf)*2048 + wid*512], AgS + (t)*32)
#define LOADB(d, t) do { \
    bq[d][0] = *(const bf16x8*)(bp[0][0] + (t)*4096); \
    bq[d][1] = *(const bf16x8*)(bp[0][1] + (t)*4096); \
    bk[d][0] = *(const bf16x8*)(bp[1][0] + (t)*4096); \
    bk[d][1] = *(const bf16x8*)(bp[1][1] + (t)*4096); \
    bv[d][0] = *(const bf16x8*)(bp[2][0] + (t)*4096); \
    bv[d][1] = *(const bf16x8*)(bp[2][1] + (t)*4096); \
  } while(0)

  // prologue issue order: A(0)[1], B(0)[6], A(1)[1]  (8 in flight)
  STAGE_A(0, 0);
  LOADB(0, 0);
  STAGE_A(1, 1);

#pragma unroll
  for (int t = 0; t < 12; ++t){
    // drain {A(t), B(t)}; keep A(t+1) in flight; publish A(t) to all waves
    if (t < 11) asm volatile("s_waitcnt vmcnt(1)\n\ts_barrier" ::: "memory");
    else        asm volatile("s_waitcnt vmcnt(0)\n\ts_barrier" ::: "memory");

    if (t < 11)  LOADB((t+1)&1, t+1);          // B first (vmcnt ledger order)
    if (t < 10)  STAGE_A((t+2)%3, t+2);

    const unsigned short* Ab = AV + (t % 3)*2048;
    bf16x8 afr[4];
#pragma unroll
    for (int ti=0; ti<4; ++ti)
      afr[ti] = *(const bf16x8*)(Ab + (ti*16 + l15)*32 + ((kg ^ rswz)*8));

    const int cur = t & 1;
    __builtin_amdgcn_s_setprio(1);
#pragma unroll
    for (int ti=0; ti<4; ++ti)
#pragma unroll
      for (int tjj=0; tjj<2; ++tjj){
        aq[ti][tjj] = __builtin_amdgcn_mfma_f32_16x16x32_bf16(afr[ti], bq[cur][tjj], aq[ti][tjj], 0,0,0);
        ak[ti][tjj] = __builtin_amdgcn_mfma_f32_16x16x32_bf16(afr[ti], bk[cur][tjj], ak[ti][tjj], 0,0,0);
        av[ti][tjj] = __builtin_amdgcn_mfma_f32_16x16x32_bf16(afr[ti], bv[cur][tjj], av[ti][tjj], 0,0,0);
      }
    __builtin_amdgcn_s_setprio(0);
  }
#undef STAGE_A
#undef LOADB

  // all waves done reading AV-as-Al; safe to overwrite AV-as-VT below
  __syncthreads();

  // bias (q pre-scaled by 1/sqrt(d)*log2e for exp2-softmax)
  const float SCL = 0.17677669529663689f * 1.4426950408889634f;
  float biasq[2], biask[2], biasv[2];
#pragma unroll
  for (int tjj=0; tjj<2; ++tjj){
    int col = hg*128 + wid*32 + tjj*16 + l15;
    biasq[tjj] = bqkv[col] * SCL;
    biask[tjj] = bqkv[384 + col];
    biasv[tjj] = bqkv[768 + col];
  }

  // ---- phase 2: pack q,k -> QK_lds[tok][q|k] (b16, swizzled); v -> VT (b64) ----
  unsigned short* QKl = QK[wid];
  unsigned short* VTl = AV + wid*2048;
#pragma unroll
  for (int ti=0; ti<4; ++ti){
#pragma unroll
    for (int tjj=0; tjj<2; ++tjj){
      const int cq = tjj*2 + (l15 >> 3);          // q chunks 0..3
      const int ck = 4 + tjj*2 + (l15 >> 3);      // k chunks 4..7
      const int sub = (l15 & 7)*2;
#pragma unroll
      for (int r=0; r<4; ++r){
        int tok = ti*16 + kg*4 + r;
        unsigned oq = (unsigned)(tok*128 + ((cq ^ (tok & 7)) << 4) + sub);
        unsigned ok = (unsigned)(tok*128 + ((ck ^ (tok & 7)) << 4) + sub);
        *(unsigned short*)((char*)QKl + oq) = f2bf(aq[ti][tjj][r]*SCL + biasq[tjj]);
        *(unsigned short*)((char*)QKl + ok) = f2bf(ak[ti][tjj][r] + biask[tjj]);
      }
      // v transposed: VT[dd][tok], 4 tokens packed as b64
      int dd = tjj*16 + l15;
      int cb = ti*2 + (kg >> 1);
      uint2 d;
      d.x = cvt_pk_bf16(av[ti][tjj][0] + biasv[tjj], av[ti][tjj][1] + biasv[tjj]);
      d.y = cvt_pk_bf16(av[ti][tjj][2] + biasv[tjj], av[ti][tjj][3] + biasv[tjj]);
      unsigned ov = (unsigned)(dd*128 + ((cb ^ (dd & 7)) << 4) + (kg & 1)*8);
      *(uint2*)((char*)VTl + ov) = d;
    }
  }

  // ---- phase 3: attention (R11-proven body; frags from wave-private LDS) ----
  const float* bt = btab + head*4096;
  f32x4 s[4][4];
#pragma unroll
  for (int ti=0; ti<4; ++ti)
#pragma unroll
    for (int tj=0; tj<4; ++tj)
      s[ti][tj] = *(const f32x4*)(bt + ((ti*4 + tj)*64 + lane)*4);

  bf16x8 kf[4], qf[4];
#pragma unroll
  for (int i=0; i<4; ++i){
    int tok = i*16 + l15;
    qf[i] = *(const bf16x8*)((char*)QKl + tok*128 + ((kg       ^ (tok & 7)) << 4));
    kf[i] = *(const bf16x8*)((char*)QKl + tok*128 + (((4 + kg) ^ (tok & 7)) << 4));
  }

  __builtin_amdgcn_s_setprio(1);
#pragma unroll
  for (int ti=0; ti<4; ++ti)
#pragma unroll
    for (int tj=0; tj<4; ++tj)
      s[ti][tj] = __builtin_amdgcn_mfma_f32_16x16x32_bf16(kf[ti], qf[tj], s[ti][tj], 0,0,0);
  __builtin_amdgcn_s_setprio(0);

  float rinv[4];
#pragma unroll
  for (int tj=0; tj<4; ++tj){
    float sum = 0.f;
#pragma unroll
    for (int ti=0; ti<4; ++ti)
#pragma unroll
      for (int r=0; r<4; ++r){
        float e = exp2f(s[ti][tj][r]);
        s[ti][tj][r] = e;
        sum += e;
      }
    sum += __shfl_xor(sum, 16);
    sum += __shfl_xor(sum, 32);
    rinv[tj] = __builtin_amdgcn_rcpf(sum);
  }

  // P reuses QK's LDS (QK dead: qf/kf already in regs; alias orders writes)
  unsigned short* Pl = QKl;
  const unsigned swzP = (unsigned)((l15 & 7) << 4);
#pragma unroll
  for (int tj=0; tj<4; ++tj){
    const float rv = rinv[tj];
    const unsigned rowb = (unsigned)((tj*16 + l15)*128);
#pragma unroll
    for (int ti=0; ti<4; ++ti){
      uint2 d;
      d.x = cvt_pk_bf16(s[ti][tj][0]*rv, s[ti][tj][1]*rv);
      d.y = cvt_pk_bf16(s[ti][tj][2]*rv, s[ti][tj][3]*rv);
      unsigned boff = (rowb + (unsigned)(ti*32 + kg*8)) ^ swzP;
      *(uint2*)((char*)Pl + boff) = d;
    }
  }

  bf16x8 vfk[2][2];
#pragma unroll
  for (int ks=0; ks<2; ++ks)
#pragma unroll
    for (int tjv=0; tjv<2; ++tjv){
      int dd = tjv*16 + l15;
      vfk[ks][tjv] = *(const bf16x8*)((char*)VTl + dd*128 + (((ks*4 + kg) ^ (dd & 7)) << 4));
    }

  f32x4 o[4][2] = {};
#pragma unroll
  for (int oti=0; oti<4; ++oti){
    bf16x8 pa[2];
#pragma unroll
    for (int ks=0; ks<2; ++ks){
      unsigned boff = ((unsigned)((oti*16 + l15)*128 + ks*64 + kg*16)) ^ swzP;
      pa[ks] = *(const bf16x8*)((char*)Pl + boff);
    }
    __builtin_amdgcn_s_setprio(1);
#pragma unroll
    for (int tjv=0; tjv<2; ++tjv){
      o[oti][tjv] = __builtin_amdgcn_mfma_f32_16x16x32_bf16(pa[0], vfk[0][tjv], o[oti][tjv], 0,0,0);
      o[oti][tjv] = __builtin_amdgcn_mfma_f32_16x16x32_bf16(pa[1], vfk[1][tjv], o[oti][tjv], 0,0,0);
    }
    __builtin_amdgcn_s_setprio(0);
  }

#pragma unroll
  for (int oti=0; oti<4; ++oti)
#pragma unroll
    for (int r=0; r<4; ++r){
      int row = oti*16 + kg*4 + r;
      if (row < 49){
        unsigned short* op = ao + ((size_t)win*49 + row)*384 + head*32 + l15;
        op[0]  = (unsigned short)cvt_pk_bf16(o[oti][0][r], o[oti][0][r]);
        op[16] = (unsigned short)cvt_pk_bf16(o[oti][1][r], o[oti][1][r]);
      }
    }
}

// ---- 256x128 tile bf16 GEMM (R11-proven, out-proj only) ----
template<int NBY>
__global__ __launch_bounds__(256) void gemm256(const unsigned short* __restrict__ A,
                                               const unsigned short* __restrict__ B,
                                               const float* __restrict__ bias,
                                               float* __restrict__ out)
{
  constexpr int K = 384;
  constexpr int NT = 12;
  __shared__ unsigned short Al[3][256*32];
  __shared__ unsigned short Bl[3][128*32];
  const int tid = threadIdx.x;
  const int lane = tid & 63, wid = tid >> 6;
  const int wr = wid >> 1, wc = wid & 1;
  const int l15 = lane & 15, kg = lane >> 4;
  const int swz = (l15 >> 1) & 3;
  const int cswz = (tid & 3) ^ ((tid >> 3) & 3);

  const int n = blockIdx.x;
  const int xcd = n & 7, s = n >> 3;
  const int panel = s / NBY, nb = s - panel*NBY;
  const int bx = panel*8 + xcd, by = nb;

  const unsigned short* Ag = A + ((size_t)bx*256 + (tid>>2))*K + cswz*8;
  const unsigned short* Bg = B + ((size_t)(by*128 + (tid>>2)))*K + cswz*8;

  f32x4 acc[8][4] = {};

#define STAGE(buf, kt) do { \
    ASYNC16(&Al[buf][wid*512],        Ag + (kt)*32); \
    ASYNC16(&Al[buf][wid*512 + 2048], Ag + (size_t)64*K  + (kt)*32); \
    ASYNC16(&Al[buf][wid*512 + 4096], Ag + (size_t)128*K + (kt)*32); \
    ASYNC16(&Al[buf][wid*512 + 6144], Ag + (size_t)192*K + (kt)*32); \
    ASYNC16(&Bl[buf][wid*512],        Bg + (kt)*32); \
    ASYNC16(&Bl[buf][wid*512 + 2048], Bg + (size_t)64*K  + (kt)*32); \
  } while(0)

  STAGE(0,0); STAGE(1,1);

#pragma unroll
  for (int t = 0; t < NT; ++t){
    if (t < NT-1) asm volatile("s_waitcnt vmcnt(6)\n\ts_barrier" ::: "memory");
    else          asm volatile("s_waitcnt vmcnt(0)\n\ts_barrier" ::: "memory");

    if (t + 2 < NT) STAGE((t+2)%3, t+2);

    const unsigned short* Ab = Al[t % 3];
    const unsigned short* Bb = Bl[t % 3];
    bf16x8 af[8], bfv[4];
#pragma unroll
    for (int ti=0; ti<8; ++ti)
      af[ti] = *(const bf16x8*)(Ab + (wr*128 + ti*16 + l15)*32 + (kg ^ swz)*8);
#pragma unroll
    for (int tj=0; tj<4; ++tj)
      bfv[tj] = *(const bf16x8*)(Bb + (wc*64 + tj*16 + l15)*32 + (kg ^ swz)*8);

    __builtin_amdgcn_s_setprio(1);
#pragma unroll
    for (int ti=0; ti<8; ++ti)
#pragma unroll
      for (int tj=0; tj<4; ++tj)
        acc[ti][tj] = __builtin_amdgcn_mfma_f32_16x16x32_bf16(af[ti], bfv[tj], acc[ti][tj], 0,0,0);
    __builtin_amdgcn_s_setprio(0);
  }
#undef STAGE

  const int rbase = bx*256 + wr*128 + kg*4;
  const int cbs = by*128 + wc*64;
  float bv[4];
#pragma unroll
  for (int tj=0; tj<4; ++tj) bv[tj] = bias[cbs + tj*16 + l15];
#pragma unroll
  for (int ti=0; ti<8; ++ti){
#pragma unroll
    for (int r=0; r<4; ++r){
      int R = rbase + ti*16 + r;
      int win = R / 49, nn = R - win*49;
      int p = nn / 7, q = nn - p*7;
      int h = (win >> 3) & 7, w = win & 7;
      size_t tok = (size_t)(win >> 6)*3136 + (size_t)((p*8 + h)*56 + q*8 + w);
      float* __restrict__ orow = out + tok*384 + cbs + l15;
#pragma unroll
      for (int tj=0; tj<4; ++tj)
        orow[tj*16] = acc[ti][tj][r] + bv[tj];
    }
  }
}

extern "C" void kernel_launch(void* const* d_in, const int* in_sizes, int n_in,
                              void* d_out, int out_size, void* d_ws, size_t ws_size,
                              hipStream_t stream)
{
  const float* x       = (const float*)d_in[0];   // 32*56*56*384
  const float* w_qkv   = (const float*)d_in[1];   // 1152*384
  const float* b_qkv   = (const float*)d_in[2];   // 1152
  const float* rel_pos = (const float*)d_in[3];   // 12*169
  const float* w_out   = (const float*)d_in[4];   // 384*384
  const float* b_out   = (const float*)d_in[5];   // 384
  float* out = (float*)d_out;                     // 100352*384

  char* ws = (char*)d_ws;
  unsigned short* wqb = (unsigned short*)ws;                  // 884736 B (frag-major)
  unsigned short* wob = (unsigned short*)(ws + 884736);       // 294912 B (row-major)
  float* btab         = (float*)(ws + 884736 + 294912);       // 196608 B
  unsigned short* xb  = (unsigned short*)(ws + 1376256);      // 38535168 elems
  unsigned short* ao  = xb + 38535168;                        // 38535168 elems

  prep_kernel<<<dim3(38040), dim3(256), 0, stream>>>(x, w_qkv, w_out, rel_pos,
                                                     xb, wqb, wob, btab);
  fqa_kernel<<<dim3(6144), dim3(256), 0, stream>>>(xb, wqb, b_qkv, btab, ao);
  gemm256<3><<<dim3(1176), dim3(256), 0, stream>>>(ao, wob, b_out, out);
}

// Round 18
// 278.965 us; speedup vs baseline: 1.6588x; 1.6588x over previous
//
#include <hip/hip_runtime.h>

typedef __attribute__((ext_vector_type(8))) short bf16x8;
typedef __attribute__((ext_vector_type(4))) float f32x4;

__device__ __forceinline__ unsigned short f2bf(float f){
  unsigned u = __builtin_bit_cast(unsigned, f);
  u += 0x7fffu + ((u >> 16) & 1u);
  return (unsigned short)(u >> 16);
}

__device__ __forceinline__ unsigned cvt_pk_bf16(float lo, float hi){
  unsigned r;
  asm("v_cvt_pk_bf16_f32 %0, %1, %2" : "=v"(r) : "v"(lo), "v"(hi));
  return r;
}

#define ASYNC16(ldsp, gp) __builtin_amdgcn_global_load_lds( \
    (const __attribute__((address_space(1))) unsigned int*)(gp), \
    (__attribute__((address_space(3))) unsigned int*)(ldsp), 16, 0, 0)

// ---- fused prep (R15-proven) ----
// [0,37632): x fp32 -> bf16 window-ordered [win*49+n][384]
// [37632,37992): Wqkv -> bf16 FRAGMENT-MAJOR (fqa layout); Wout -> bf16 row-major
// [37992,38040): btab fragment-major, log2e-scaled, -inf mask k>=49.
__global__ __launch_bounds__(256) void prep_kernel(const float* __restrict__ x,
                                                   const float* __restrict__ wq,
                                                   const float* __restrict__ wo,
                                                   const float* __restrict__ rel_pos,
                                                   unsigned short* __restrict__ xb,
                                                   unsigned short* __restrict__ wqb,
                                                   unsigned short* __restrict__ wob,
                                                   float* __restrict__ btab){
  const int bid = blockIdx.x;
  if (bid < 37632){
    int idx = bid*256 + threadIdx.x;               // 100352*96 threads, 4 ch each
    int token = idx / 96, j = idx - token*96;
    int b = token / 3136, rem = token - b*3136;
    int rr = rem / 56, cp = rem - rr*56;
    int p = rr >> 3, h = rr & 7, q = cp >> 3, w = cp & 7;
    int orow = ((b*8 + h)*8 + w)*49 + p*7 + q;
    float4 v = *(const float4*)(x + (size_t)idx*4);
    ushort4 o;
    o.x = f2bf(v.x); o.y = f2bf(v.y); o.z = f2bf(v.z); o.w = f2bf(v.w);
    *(ushort4*)(xb + (size_t)orow*384 + j*4) = o;
  } else if (bid < 37992){
    int idx = (bid - 37632)*256 + threadIdx.x;     // 92160 threads
    if (idx < 55296){                              // Wqkv frag-major, 8 elems
      int lane = idx & 63;
      int r = idx >> 6;                            // 0..863
      int wt = r & 7; int r2 = r >> 3;             // 0..107
      int t = r2 % 12, gi = r2 / 12;               // gi 0..8
      int hgp = gi / 3, m = gi - hgp*3;
      int row = m*384 + hgp*128 + (wt>>1)*32 + (wt&1)*16 + (lane & 15);
      int col = t*32 + (lane >> 4)*8;
      const float* s = wq + (size_t)row*384 + col;
      float4 v1 = *(const float4*)(s);
      float4 v2 = *(const float4*)(s + 4);
      ushort4 o1, o2;
      o1.x=f2bf(v1.x); o1.y=f2bf(v1.y); o1.z=f2bf(v1.z); o1.w=f2bf(v1.w);
      o2.x=f2bf(v2.x); o2.y=f2bf(v2.y); o2.z=f2bf(v2.z); o2.w=f2bf(v2.w);
      unsigned short* dst = wqb + (size_t)idx*8;
      *(ushort4*)(dst)     = o1;
      *(ushort4*)(dst + 4) = o2;
    } else {                                       // Wout row-major, 4 elems
      int k = idx - 55296;                         // 36864 threads
      float4 v = *(const float4*)(wo + (size_t)k*4);
      ushort4 o; o.x=f2bf(v.x); o.y=f2bf(v.y); o.z=f2bf(v.z); o.w=f2bf(v.w);
      *(ushort4*)(wob + (size_t)k*4) = o;
    }
  } else {
    int idx = (bid - 37992)*256 + threadIdx.x;     // 12288 threads
    int head = idx >> 10, rem = idx & 1023;
    int fi = rem >> 6, lane = rem & 63;
    int ti = fi >> 2, tj = fi & 3;
    int qq = tj*16 + (lane & 15);
    int kb = ti*16 + (lane >> 4)*4;
    float4 v; float* vp = (float*)&v;
#pragma unroll
    for (int r=0; r<4; ++r){
      int kk = kb + r;
      float val;
      if (kk >= 49) val = -__builtin_inff();
      else if (qq >= 49) val = 0.f;
      else {
        int ip = qq/7, iq = qq - ip*7, jp = kk/7, jq = kk - jp*7;
        val = rel_pos[head*169 + (ip-jp+6)*13 + (iq-jq+6)] * 1.4426950408889634f;
      }
      vp[r] = val;
    }
    *(float4*)(btab + (size_t)idx*4) = v;
  }
}

// ---- FUSED qkv-projection + windowed attention, v4 ----
// = R16-verified kernel + AV union (Al dead after ph1 shares 16KB with VT;
// one __syncthreads() between), LDS 60->48KB so the HW occupancy calculator
// can fit 3 blocks/CU.  CRITICAL (R17 lesson): launch_bounds stays (256,2) --
// pinning 3 waves/EU forced VGPR<=84 and spilled the 96-reg accumulator set
// to scratch (WRITE_SIZE 75->911MB).  Let regalloc keep 96 VGPR.
__global__ __launch_bounds__(256, 2) void fqa_kernel(const unsigned short* __restrict__ xb,
                                                     const unsigned short* __restrict__ Wf,
                                                     const float* __restrict__ bqkv,
                                                     const float* __restrict__ btab,
                                                     unsigned short* __restrict__ ao)
{
  __shared__ unsigned short AV[8192];      // 16KB: Al[3][2048] (ph1) ∪ VT[4][2048] (ph2/3)
  __shared__ unsigned short QK[4][4096];   // 32KB [tok64][q32|k32] swizzled; reused as P
  const int tid = threadIdx.x, lane = tid & 63, wid = tid >> 6;
  const int l15 = lane & 15, kg = lane >> 4;
  const int win = blockIdx.x & 2047;
  const int hg  = blockIdx.x >> 11;              // 0..2
  const int head = hg*4 + wid;

  // ---- phase 1: qkv GEMM (M=64 window rows, per-wave N=32 dd-cols, K=384) ----
  int srowg = win*49 + (tid >> 2);
  if (srowg > 100351) srowg = 100351;            // finite clamp (last window)
  const int cswz = (tid & 3) ^ ((tid >> 3) & 3);
  const unsigned short* AgS = xb + (size_t)srowg*384 + cswz*8;
  const int rswz = (l15 >> 1) & 3;               // read-side chunk XOR

  const unsigned short* bp[3][2];
#pragma unroll
  for (int m=0; m<3; ++m)
#pragma unroll
    for (int tjj=0; tjj<2; ++tjj)
      bp[m][tjj] = Wf + ((size_t)((hg*3 + m)*12)*8 + wid*2 + tjj)*512 + lane*8;

  f32x4 aq[4][2] = {}, ak[4][2] = {}, av[4][2] = {};
  bf16x8 bq[2][2], bk[2][2], bv[2][2];

#define STAGE_A(buf, t) ASYNC16(&AV[(buf)*2048 + wid*512], AgS + (t)*32)
#define LOADB(d, t) do { \
    bq[d][0] = *(const bf16x8*)(bp[0][0] + (t)*4096); \
    bq[d][1] = *(const bf16x8*)(bp[0][1] + (t)*4096); \
    bk[d][0] = *(const bf16x8*)(bp[1][0] + (t)*4096); \
    bk[d][1] = *(const bf16x8*)(bp[1][1] + (t)*4096); \
    bv[d][0] = *(const bf16x8*)(bp[2][0] + (t)*4096); \
    bv[d][1] = *(const bf16x8*)(bp[2][1] + (t)*4096); \
  } while(0)

  // prologue issue order: A(0)[1], B(0)[6], A(1)[1]  (8 in flight)
  STAGE_A(0, 0);
  LOADB(0, 0);
  STAGE_A(1, 1);

#pragma unroll
  for (int t = 0; t < 12; ++t){
    // drain {A(t), B(t)}; keep A(t+1) in flight; publish A(t) to all waves
    if (t < 11) asm volatile("s_waitcnt vmcnt(1)\n\ts_barrier" ::: "memory");
    else        asm volatile("s_waitcnt vmcnt(0)\n\ts_barrier" ::: "memory");

    if (t < 11)  LOADB((t+1)&1, t+1);          // B first (vmcnt ledger order)
    if (t < 10)  STAGE_A((t+2)%3, t+2);

    const unsigned short* Ab = AV + (t % 3)*2048;
    bf16x8 afr[4];
#pragma unroll
    for (int ti=0; ti<4; ++ti)
      afr[ti] = *(const bf16x8*)(Ab + (ti*16 + l15)*32 + ((kg ^ rswz)*8));

    const int cur = t & 1;
    __builtin_amdgcn_s_setprio(1);
#pragma unroll
    for (int ti=0; ti<4; ++ti)
#pragma unroll
      for (int tjj=0; tjj<2; ++tjj){
        aq[ti][tjj] = __builtin_amdgcn_mfma_f32_16x16x32_bf16(afr[ti], bq[cur][tjj], aq[ti][tjj], 0,0,0);
        ak[ti][tjj] = __builtin_amdgcn_mfma_f32_16x16x32_bf16(afr[ti], bk[cur][tjj], ak[ti][tjj], 0,0,0);
        av[ti][tjj] = __builtin_amdgcn_mfma_f32_16x16x32_bf16(afr[ti], bv[cur][tjj], av[ti][tjj], 0,0,0);
      }
    __builtin_amdgcn_s_setprio(0);
  }
#undef STAGE_A
#undef LOADB

  // all waves done reading AV-as-Al; safe to overwrite AV-as-VT below
  __syncthreads();

  // bias (q pre-scaled by 1/sqrt(d)*log2e for exp2-softmax)
  const float SCL = 0.17677669529663689f * 1.4426950408889634f;
  float biasq[2], biask[2], biasv[2];
#pragma unroll
  for (int tjj=0; tjj<2; ++tjj){
    int col = hg*128 + wid*32 + tjj*16 + l15;
    biasq[tjj] = bqkv[col] * SCL;
    biask[tjj] = bqkv[384 + col];
    biasv[tjj] = bqkv[768 + col];
  }

  // ---- phase 2: pack q,k -> QK_lds[tok][q|k] (b16, swizzled); v -> VT (b64) ----
  unsigned short* QKl = QK[wid];
  unsigned short* VTl = AV + wid*2048;
#pragma unroll
  for (int ti=0; ti<4; ++ti){
#pragma unroll
    for (int tjj=0; tjj<2; ++tjj){
      const int cq = tjj*2 + (l15 >> 3);          // q chunks 0..3
      const int ck = 4 + tjj*2 + (l15 >> 3);      // k chunks 4..7
      const int sub = (l15 & 7)*2;
#pragma unroll
      for (int r=0; r<4; ++r){
        int tok = ti*16 + kg*4 + r;
        unsigned oq = (unsigned)(tok*128 + ((cq ^ (tok & 7)) << 4) + sub);
        unsigned ok = (unsigned)(tok*128 + ((ck ^ (tok & 7)) << 4) + sub);
        *(unsigned short*)((char*)QKl + oq) = f2bf(aq[ti][tjj][r]*SCL + biasq[tjj]);
        *(unsigned short*)((char*)QKl + ok) = f2bf(ak[ti][tjj][r] + biask[tjj]);
      }
      // v transposed: VT[dd][tok], 4 tokens packed as b64
      int dd = tjj*16 + l15;
      int cb = ti*2 + (kg >> 1);
      uint2 d;
      d.x = cvt_pk_bf16(av[ti][tjj][0] + biasv[tjj], av[ti][tjj][1] + biasv[tjj]);
      d.y = cvt_pk_bf16(av[ti][tjj][2] + biasv[tjj], av[ti][tjj][3] + biasv[tjj]);
      unsigned ov = (unsigned)(dd*128 + ((cb ^ (dd & 7)) << 4) + (kg & 1)*8);
      *(uint2*)((char*)VTl + ov) = d;
    }
  }

  // ---- phase 3: attention (R11-proven body; frags from wave-private LDS) ----
  const float* bt = btab + head*4096;
  f32x4 s[4][4];
#pragma unroll
  for (int ti=0; ti<4; ++ti)
#pragma unroll
    for (int tj=0; tj<4; ++tj)
      s[ti][tj] = *(const f32x4*)(bt + ((ti*4 + tj)*64 + lane)*4);

  bf16x8 kf[4], qf[4];
#pragma unroll
  for (int i=0; i<4; ++i){
    int tok = i*16 + l15;
    qf[i] = *(const bf16x8*)((char*)QKl + tok*128 + ((kg       ^ (tok & 7)) << 4));
    kf[i] = *(const bf16x8*)((char*)QKl + tok*128 + (((4 + kg) ^ (tok & 7)) << 4));
  }

  __builtin_amdgcn_s_setprio(1);
#pragma unroll
  for (int ti=0; ti<4; ++ti)
#pragma unroll
    for (int tj=0; tj<4; ++tj)
      s[ti][tj] = __builtin_amdgcn_mfma_f32_16x16x32_bf16(kf[ti], qf[tj], s[ti][tj], 0,0,0);
  __builtin_amdgcn_s_setprio(0);

  float rinv[4];
#pragma unroll
  for (int tj=0; tj<4; ++tj){
    float sum = 0.f;
#pragma unroll
    for (int ti=0; ti<4; ++ti)
#pragma unroll
      for (int r=0; r<4; ++r){
        float e = exp2f(s[ti][tj][r]);
        s[ti][tj][r] = e;
        sum += e;
      }
    sum += __shfl_xor(sum, 16);
    sum += __shfl_xor(sum, 32);
    rinv[tj] = __builtin_amdgcn_rcpf(sum);
  }

  // P reuses QK's LDS (QK dead: qf/kf already in regs; alias orders writes)
  unsigned short* Pl = QKl;
  const unsigned swzP = (unsigned)((l15 & 7) << 4);
#pragma unroll
  for (int tj=0; tj<4; ++tj){
    const float rv = rinv[tj];
    const unsigned rowb = (unsigned)((tj*16 + l15)*128);
#pragma unroll
    for (int ti=0; ti<4; ++ti){
      uint2 d;
      d.x = cvt_pk_bf16(s[ti][tj][0]*rv, s[ti][tj][1]*rv);
      d.y = cvt_pk_bf16(s[ti][tj][2]*rv, s[ti][tj][3]*rv);
      unsigned boff = (rowb + (unsigned)(ti*32 + kg*8)) ^ swzP;
      *(uint2*)((char*)Pl + boff) = d;
    }
  }

  bf16x8 vfk[2][2];
#pragma unroll
  for (int ks=0; ks<2; ++ks)
#pragma unroll
    for (int tjv=0; tjv<2; ++tjv){
      int dd = tjv*16 + l15;
      vfk[ks][tjv] = *(const bf16x8*)((char*)VTl + dd*128 + (((ks*4 + kg) ^ (dd & 7)) << 4));
    }

  f32x4 o[4][2] = {};
#pragma unroll
  for (int oti=0; oti<4; ++oti){
    bf16x8 pa[2];
#pragma unroll
    for (int ks=0; ks<2; ++ks){
      unsigned boff = ((unsigned)((oti*16 + l15)*128 + ks*64 + kg*16)) ^ swzP;
      pa[ks] = *(const bf16x8*)((char*)Pl + boff);
    }
    __builtin_amdgcn_s_setprio(1);
#pragma unroll
    for (int tjv=0; tjv<2; ++tjv){
      o[oti][tjv] = __builtin_amdgcn_mfma_f32_16x16x32_bf16(pa[0], vfk[0][tjv], o[oti][tjv], 0,0,0);
      o[oti][tjv] = __builtin_amdgcn_mfma_f32_16x16x32_bf16(pa[1], vfk[1][tjv], o[oti][tjv], 0,0,0);
    }
    __builtin_amdgcn_s_setprio(0);
  }

#pragma unroll
  for (int oti=0; oti<4; ++oti)
#pragma unroll
    for (int r=0; r<4; ++r){
      int row = oti*16 + kg*4 + r;
      if (row < 49){
        unsigned short* op = ao + ((size_t)win*49 + row)*384 + head*32 + l15;
        op[0]  = (unsigned short)cvt_pk_bf16(o[oti][0][r], o[oti][0][r]);
        op[16] = (unsigned short)cvt_pk_bf16(o[oti][1][r], o[oti][1][r]);
      }
    }
}

// ---- 256x128 tile bf16 GEMM (R11-proven, out-proj only) ----
template<int NBY>
__global__ __launch_bounds__(256) void gemm256(const unsigned short* __restrict__ A,
                                               const unsigned short* __restrict__ B,
                                               const float* __restrict__ bias,
                                               float* __restrict__ out)
{
  constexpr int K = 384;
  constexpr int NT = 12;
  __shared__ unsigned short Al[3][256*32];
  __shared__ unsigned short Bl[3][128*32];
  const int tid = threadIdx.x;
  const int lane = tid & 63, wid = tid >> 6;
  const int wr = wid >> 1, wc = wid & 1;
  const int l15 = lane & 15, kg = lane >> 4;
  const int swz = (l15 >> 1) & 3;
  const int cswz = (tid & 3) ^ ((tid >> 3) & 3);

  const int n = blockIdx.x;
  const int xcd = n & 7, s = n >> 3;
  const int panel = s / NBY, nb = s - panel*NBY;
  const int bx = panel*8 + xcd, by = nb;

  const unsigned short* Ag = A + ((size_t)bx*256 + (tid>>2))*K + cswz*8;
  const unsigned short* Bg = B + ((size_t)(by*128 + (tid>>2)))*K + cswz*8;

  f32x4 acc[8][4] = {};

#define STAGE(buf, kt) do { \
    ASYNC16(&Al[buf][wid*512],        Ag + (kt)*32); \
    ASYNC16(&Al[buf][wid*512 + 2048], Ag + (size_t)64*K  + (kt)*32); \
    ASYNC16(&Al[buf][wid*512 + 4096], Ag + (size_t)128*K + (kt)*32); \
    ASYNC16(&Al[buf][wid*512 + 6144], Ag + (size_t)192*K + (kt)*32); \
    ASYNC16(&Bl[buf][wid*512],        Bg + (kt)*32); \
    ASYNC16(&Bl[buf][wid*512 + 2048], Bg + (size_t)64*K  + (kt)*32); \
  } while(0)

  STAGE(0,0); STAGE(1,1);

#pragma unroll
  for (int t = 0; t < NT; ++t){
    if (t < NT-1) asm volatile("s_waitcnt vmcnt(6)\n\ts_barrier" ::: "memory");
    else          asm volatile("s_waitcnt vmcnt(0)\n\ts_barrier" ::: "memory");

    if (t + 2 < NT) STAGE((t+2)%3, t+2);

    const unsigned short* Ab = Al[t % 3];
    const unsigned short* Bb = Bl[t % 3];
    bf16x8 af[8], bfv[4];
#pragma unroll
    for (int ti=0; ti<8; ++ti)
      af[ti] = *(const bf16x8*)(Ab + (wr*128 + ti*16 + l15)*32 + (kg ^ swz)*8);
#pragma unroll
    for (int tj=0; tj<4; ++tj)
      bfv[tj] = *(const bf16x8*)(Bb + (wc*64 + tj*16 + l15)*32 + (kg ^ swz)*8);

    __builtin_amdgcn_s_setprio(1);
#pragma unroll
    for (int ti=0; ti<8; ++ti)
#pragma unroll
      for (int tj=0; tj<4; ++tj)
        acc[ti][tj] = __builtin_amdgcn_mfma_f32_16x16x32_bf16(af[ti], bfv[tj], acc[ti][tj], 0,0,0);
    __builtin_amdgcn_s_setprio(0);
  }
#undef STAGE

  const int rbase = bx*256 + wr*128 + kg*4;
  const int cbs = by*128 + wc*64;
  float bv[4];
#pragma unroll
  for (int tj=0; tj<4; ++tj) bv[tj] = bias[cbs + tj*16 + l15];
#pragma unroll
  for (int ti=0; ti<8; ++ti){
#pragma unroll
    for (int r=0; r<4; ++r){
      int R = rbase + ti*16 + r;
      int win = R / 49, nn = R - win*49;
      int p = nn / 7, q = nn - p*7;
      int h = (win >> 3) & 7, w = win & 7;
      size_t tok = (size_t)(win >> 6)*3136 + (size_t)((p*8 + h)*56 + q*8 + w);
      float* __restrict__ orow = out + tok*384 + cbs + l15;
#pragma unroll
      for (int tj=0; tj<4; ++tj)
        orow[tj*16] = acc[ti][tj][r] + bv[tj];
    }
  }
}

extern "C" void kernel_launch(void* const* d_in, const int* in_sizes, int n_in,
                              void* d_out, int out_size, void* d_ws, size_t ws_size,
                              hipStream_t stream)
{
  const float* x       = (const float*)d_in[0];   // 32*56*56*384
  const float* w_qkv   = (const float*)d_in[1];   // 1152*384
  const float* b_qkv   = (const float*)d_in[2];   // 1152
  const float* rel_pos = (const float*)d_in[3];   // 12*169
  const float* w_out   = (const float*)d_in[4];   // 384*384
  const float* b_out   = (const float*)d_in[5];   // 384
  float* out = (float*)d_out;                     // 100352*384

  char* ws = (char*)d_ws;
  unsigned short* wqb = (unsigned short*)ws;                  // 884736 B (frag-major)
  unsigned short* wob = (unsigned short*)(ws + 884736);       // 294912 B (row-major)
  float* btab         = (float*)(ws + 884736 + 294912);       // 196608 B
  unsigned short* xb  = (unsigned short*)(ws + 1376256);      // 38535168 elems
  unsigned short* ao  = xb + 38535168;                        // 38535168 elems

  prep_kernel<<<dim3(38040), dim3(256), 0, stream>>>(x, w_qkv, w_out, rel_pos,
                                                     xb, wqb, wob, btab);
  fqa_kernel<<<dim3(6144), dim3(256), 0, stream>>>(xb, wqb, b_qkv, btab, ao);
  gemm256<3><<<dim3(1176), dim3(256), 0, stream>>>(ao, wob, b_out, out);
}